// Round 2
// baseline (83.757 us; speedup 1.0000x reference)
//
#include <hip/hip_runtime.h>

// LinkPredictor: q[i,j] = relu(z_i@W1a + z_j@W1b + b1) @ W2 + b2, N=1024, D=128.
// R2 post-mortem: occupancy bump gave only -2.5us -> LDS-staged pair structure
// itself is the cost (3B LDS/elem + barrier + staging ~= VALU floor; nothing to
// hide behind at 2 waves/SIMD). R3: LDS-FREE pair kernel.
//   lane = j  -> out writes coalesced, pj[j,d] per-lane from pjT[d][j] (b32
//                coalesced; proj writes pjT via float4, it holds 4 consecutive j)
//   i,d uniform -> pic[i,d], W2[d] become SGPR operands (SMEM pipe, not LDS/VALU)
//   inner op = v_add_f32(s,v); v_max_f32(,0); v_fma_f32(s) = exactly 3 VALU/elem
// Floor: 402M lane-ops / 78.6T = 5.1us VALU; pjT L2 re-read 128MB ~3.7us hidden.
// Grid 1024 blocks = 4 blocks/CU = 4 waves/SIMD for latency hiding.

#define NN 1024
#define DD 128
#define IT 4     // i-rows per pair block
#define DC 32    // d-chunk held in registers (pjv)

__global__ __launch_bounds__(256) void proj_kernel(
    const float* __restrict__ z,
    const float* __restrict__ W1,
    const float* __restrict__ b1,
    float* __restrict__ pic,
    float* __restrict__ pjT)
{
    const int i0 = blockIdx.x * 4;          // 4 z-rows per block, grid = 256
    const int t = threadIdx.x;
    const int half = t >> 7;                // wave-uniform: waves 0-1 -> pic, 2-3 -> pjT
    const int d = t & (DD - 1);
    const float* __restrict__ Wcol = W1 + half * DD * DD + d;
    const float* __restrict__ z0 = z + i0 * DD;   // block-uniform -> scalar loads

    float a0 = 0.f, a1 = 0.f, a2 = 0.f, a3 = 0.f;
    #pragma unroll 8
    for (int k = 0; k < DD; ++k) {
        const float w = Wcol[k * DD];       // coalesced (lanes d contiguous)
        a0 = fmaf(z0[k], w, a0);
        a1 = fmaf(z0[DD + k], w, a1);
        a2 = fmaf(z0[2 * DD + k], w, a2);
        a3 = fmaf(z0[3 * DD + k], w, a3);
    }
    if (half == 0) {
        const float bb = b1[d];             // fold bias into pic
        pic[(i0 + 0) * DD + d] = a0 + bb;
        pic[(i0 + 1) * DD + d] = a1 + bb;
        pic[(i0 + 2) * DD + d] = a2 + bb;
        pic[(i0 + 3) * DD + d] = a3 + bb;
    } else {
        // This thread owns pj[i0..i0+3][d] = pjT[d][i0..i0+3]: one float4 store.
        // Lanes hit different pjT rows (stride 4KB) but only 16B each; 2MB total
        // L2 write traffic -- negligible.
        *(float4*)(pjT + (size_t)d * NN + i0) = make_float4(a0, a1, a2, a3);
    }
}

__global__ __launch_bounds__(256) void pair_kernel(
    const float* __restrict__ pic,
    const float* __restrict__ pjT,
    const float* __restrict__ W2,
    const float* __restrict__ b2,
    float* __restrict__ out)
{
    const int t  = threadIdx.x;
    const int j  = blockIdx.x * 256 + t;    // lane owns one j -> coalesced
    const int i0 = blockIdx.y * IT;

    float acc[IT];
    #pragma unroll
    for (int ii = 0; ii < IT; ++ii) acc[ii] = 0.f;

    const float* __restrict__ pr = pic + i0 * DD;   // uniform base

    for (int dc = 0; dc < DD; dc += DC) {   // 4 iterations, not unrolled (I$)
        float pjv[DC];
        #pragma unroll
        for (int u = 0; u < DC; ++u)
            pjv[u] = pjT[(size_t)(dc + u) * NN + j];   // coalesced b32

        #pragma unroll
        for (int ii = 0; ii < IT; ++ii) {
            #pragma unroll
            for (int u = 0; u < DC; ++u) {
                // pr[..], W2[..] wave-uniform -> SGPR operands (1 SGPR/op legal):
                //   v_add_f32 v, s_pi, v_pjv ; v_max_f32 v, v, 0 ; v_fma_f32 acc, v, s_w, acc
                acc[ii] = fmaf(fmaxf(pr[ii * DD + dc + u] + pjv[u], 0.f),
                               W2[dc + u], acc[ii]);
            }
        }
    }

    const float bb = b2[0];
    #pragma unroll
    for (int ii = 0; ii < IT; ++ii)
        out[(size_t)(i0 + ii) * NN + j] = acc[ii] + bb;   // coalesced b32
}

extern "C" void kernel_launch(void* const* d_in, const int* in_sizes, int n_in,
                              void* d_out, int out_size, void* d_ws, size_t ws_size,
                              hipStream_t stream)
{
    const float* z  = (const float*)d_in[0];   // [1024,128]
    const float* W1 = (const float*)d_in[1];   // [256,128] row-major
    const float* b1 = (const float*)d_in[2];   // [128]
    const float* W2 = (const float*)d_in[3];   // [128]
    const float* b2 = (const float*)d_in[4];   // [1]
    float* out = (float*)d_out;                // [1024*1024]

    float* pic = (float*)d_ws;                 // [1024,128] fp32, b1 folded
    float* pjT = pic + NN * DD;                // [128,1024] fp32, transposed

    proj_kernel<<<NN / 4, 256, 0, stream>>>(z, W1, b1, pic, pjT);

    dim3 grid(NN / 256, NN / IT);              // (4, 256) = 1024 blocks = 4/CU
    pair_kernel<<<grid, 256, 0, stream>>>(pic, pjT, W2, b2, out);
}